// Round 18
// baseline (331.002 us; speedup 1.0000x reference)
//
#include <hip/hip_runtime.h>
#include <math.h>

// Relational Network fused pipeline for MI355X (gfx950).
// B=32, D=64, K=26, QST=256, G=[512x6, 28], AGG at layer 4.
//
// Round 23 = round 22's async-DMA B ring with the RACE FIXED:
//  - R22 failed correctness (absmax 38): global_load_lds completion is
//    tracked by vmcnt and the compiler has NO dataflow edge from a DMA to
//    a ds_read of the same LDS address -> slot reads ran before the DMA
//    landed. Fix is the HK/AITER counted-vmcnt discipline:
//      (1) s_waitcnt vmcnt(4) (+ sched_barrier(0), rule #18) at the top of
//          each k-step before that slot's ds_reads: 8 DMAs outstanding in
//          steady state, oldest 4 are this slot's -> vmcnt(4) is exact.
//      (2) slot-reload DMAs issued AFTER cluster 3 (DS returns in-order, so
//          cluster3's lgkm wait proves all 4 slot reads completed -> no
//          write-before-read hazard; issue->use ~1 full step > L2 latency).
//      (3) priming DMAs grouped slot0 then slot1.
//  - Everything else as round 22: Bst[2][8][4KB] ring (-32 arch regs vs the
//    X/Y register dbuf), hsm single-buffer, 6 barriers/block, vectorized
//    k_prep, 4-way split tail.

typedef __attribute__((ext_vector_type(8))) short bf16x8;   // 8 bf16 in 4 VGPRs
typedef __attribute__((ext_vector_type(4))) float f32x4;    // MFMA 16x16 accumulator
typedef __attribute__((ext_vector_type(4))) unsigned int u32x4;

__device__ __forceinline__ unsigned short f2bf(float f) {
    union { float f; unsigned u; } x; x.f = f;
    unsigned r = x.u + 0x7fffu + ((x.u >> 16) & 1u);   // RNE
    return (unsigned short)(r >> 16);
}

// async 16B global->LDS DMA (dest: wave-uniform base + lane*16;
// src: per-lane global address)
#define GLDS16(G, L)                                                        \
    __builtin_amdgcn_global_load_lds(                                       \
        (const __attribute__((address_space(1))) void*)(G),                 \
        (__attribute__((address_space(3))) void*)(L), 16, 0, 0)

// counted wait: oldest 4 of the 8 outstanding DMAs (this slot's) must land
#define WAIT_SLOT()                                        \
    asm volatile("s_waitcnt vmcnt(4)" ::: "memory");       \
    __builtin_amdgcn_sched_barrier(0);

// ---------------- pack / transpose weights (vectorized) ----------------
// Wp layout per layer: [wave(8)][s(16)][jj(4)][lane(64)][j(8)] bf16,
//   value = W[n][k], n = (wave*4+jj)*16 + (lane&15), k = s*32 + (lane>>4)*8 + j.
// W0p: same with s(2) over padded K=64 (k >= 52 -> 0).
// W4v/W5v: fp32 [k/4][512 out][4] so tail threads stream float4.
#define NPV_WP   98304            // 3 * 512 * 64   (8 bf16/thread)
#define NPV_W0P  4096             // 512 * 8        (8 bf16/thread)
#define NPV_W4   98304            // 768*512/4      (4 f32/thread)
#define NPV_W5   65536            // 512*512/4
#define NPV_TOTAL (NPV_WP + NPV_W0P + NPV_W4 + NPV_W5)   // 266240 = 1040*256
__global__ void k_prep(const float* __restrict__ W1, const float* __restrict__ W2,
                       const float* __restrict__ W3, const float* __restrict__ W0,
                       const float* __restrict__ W4, const float* __restrict__ W5,
                       unsigned short* __restrict__ Wp,   // [3][262144] bf16
                       unsigned short* __restrict__ W0p,  // [32768] bf16
                       float* __restrict__ W4v,           // [192][512][4] fp32
                       float* __restrict__ W5v)           // [128][512][4] fp32
{
    int f = blockIdx.x * 256 + threadIdx.x;
    if (f < NPV_WP) {
        int l = f >> 15, r = f & 32767;
        int n = r >> 6, kq = r & 63;                 // k0 = kq*8
        const float* W = (l == 0) ? W1 : (l == 1) ? W2 : W3;
        const float* src = W + n * 512 + kq * 8;
        int s = kq >> 2, q4 = kq & 3;
        int wv = n >> 6, jj = (n >> 4) & 3, i16 = n & 15;
        int lane = q4 * 16 + i16;
        unsigned w[4];
        #pragma unroll
        for (int h = 0; h < 4; ++h)
            w[h] = (unsigned)f2bf(src[h * 2]) | ((unsigned)f2bf(src[h * 2 + 1]) << 16);
        *(u32x4*)(Wp + (size_t)l * 262144 + ((((wv * 16 + s) * 4 + jj) * 64 + lane) << 3))
            = (u32x4){w[0], w[1], w[2], w[3]};
    } else if (f < NPV_WP + NPV_W0P) {
        int g = f - NPV_WP;
        int n = g >> 3, kq = g & 7;
        int s = kq >> 2, q4 = kq & 3;
        int wv = n >> 6, jj = (n >> 4) & 3, i16 = n & 15;
        int lane = q4 * 16 + i16;
        unsigned w[4];
        #pragma unroll
        for (int h = 0; h < 4; ++h) {
            int k0 = kq * 8 + h * 2, k1 = k0 + 1;
            float f0 = (k0 < 52) ? W0[n * 52 + k0] : 0.f;
            float f1 = (k1 < 52) ? W0[n * 52 + k1] : 0.f;
            w[h] = (unsigned)f2bf(f0) | ((unsigned)f2bf(f1) << 16);
        }
        *(u32x4*)(W0p + ((((wv * 2 + s) * 4 + jj) * 64 + lane) << 3))
            = (u32x4){w[0], w[1], w[2], w[3]};
    } else if (f < NPV_WP + NPV_W0P + NPV_W4) {
        int g = f - (NPV_WP + NPV_W0P);
        int o = g / 192, kb = g % 192;
        float4 w = *(const float4*)(W4 + (size_t)o * 768 + kb * 4);
        *(float4*)(W4v + (size_t)kb * 2048 + o * 4) = w;
    } else {
        int g = f - (NPV_WP + NPV_W0P + NPV_W4);
        int o = g >> 7, kb = g & 127;
        float4 w = *(const float4*)(W5 + (size_t)o * 512 + kb * 4);
        *(float4*)(W5v + (size_t)kb * 2048 + o * 4) = w;
    }
}

// ---------------- h-store epilogue: bias + relu + bf16 LDS write ----
// Granule-column-major target: byte = (col>>3)*1024 + (row ^ ((col>>3)&7))*16
//                                    + (col&7)*2.
// DPP quad_perm swap on f32, then v_cvt_pk_bf16_f32 packs (col, col+1) into
// one dword; even lanes write ds_write_b32.
__device__ __forceinline__ void store_h(const f32x4 (&acc)[4][4], const float* __restrict__ bl,
                                        unsigned short* hbuf, int wave, int i16, int q4, int lane)
{
    char* base = (char*)hbuf;
    #pragma unroll
    for (int j = 0; j < 4; ++j) {
        int col = (wave * 4 + j) * 16 + i16;
        int g = col >> 3;
        int e = g & 7;
        float bb = bl[col];
        char* colbase = base + g * 1024 + ((col & 7) << 1);
        #pragma unroll
        for (int mt = 0; mt < 4; ++mt) {
            #pragma unroll
            for (int r = 0; r < 4; ++r) {
                int row = mt * 16 + q4 * 4 + r;
                float v = fmaxf(acc[mt][j][r] + bb, 0.f);
                int vi = __float_as_int(v);
                // quad_perm [1,0,3,2]: each lane gets partner (lane^1)'s f32
                int swi = __builtin_amdgcn_update_dpp(0, vi, 0xB1, 0xF, 0xF, true);
                if ((lane & 1) == 0) {
                    unsigned pk;
                    asm("v_cvt_pk_bf16_f32 %0, %1, %2" : "=v"(pk) : "v"(vi), "v"(swi));
                    int slot = row ^ e;
                    *(unsigned*)(colbase + slot * 16) = pk;
                }
            }
        }
    }
}

#define CLUSTER(AV0, AV1, AV2, AV3, BV, JJ)                                              \
    __builtin_amdgcn_s_setprio(1);                                                      \
    acc[0][JJ] = __builtin_amdgcn_mfma_f32_16x16x32_bf16(AV0, BV, acc[0][JJ], 0, 0, 0); \
    acc[1][JJ] = __builtin_amdgcn_mfma_f32_16x16x32_bf16(AV1, BV, acc[1][JJ], 0, 0, 0); \
    acc[2][JJ] = __builtin_amdgcn_mfma_f32_16x16x32_bf16(AV2, BV, acc[2][JJ], 0, 0, 0); \
    acc[3][JJ] = __builtin_amdgcn_mfma_f32_16x16x32_bf16(AV3, BV, acc[3][JJ], 0, 0, 0); \
    __builtin_amdgcn_s_setprio(0);                                                      \
    __builtin_amdgcn_sched_barrier(0);

// ---------------- fused layers 0..3 ----------------
// One block per (b,p): 64 pair-rows. h tile 64x512 bf16 single-buffered in
// LDS (granule-column-major: [g=k>>3][slot=row^(g&7)][8 shorts]).
// B weights stream through Bst[2 slots][8 waves][4KB] via async DMA with
// counted vmcnt waits. 8 waves; wave w computes cols [w*64, w*64+64).
__global__ __launch_bounds__(512, 2) void k_fused(
    const float* __restrict__ x,
    const unsigned short* __restrict__ Wp,
    const unsigned short* __restrict__ W0p,
    const float* __restrict__ b0, const float* __restrict__ b1,
    const float* __restrict__ b2, const float* __restrict__ b3,
    float* __restrict__ P)
{
    __shared__ __align__(16) unsigned short hsm[64 * 512];      // 64 KiB
    __shared__ __align__(16) unsigned short Bst[2 * 8 * 2048];  // 64 KiB B ring
    __shared__ __align__(16) unsigned short xs[8 * 64 * 8];     // 8 KiB x-pair tile
    int t = threadIdx.x;
    int blk = blockIdx.x;
    int b = blk >> 6, p = blk & 63;

    // ---- stage xs: [g(8)][slot=row^g][8] bf16 of [x[b,row,:26] | x[b,p,:26] | 0] ----
    {
        int row = t >> 3, gr = t & 7;
        const float* xq = x + (size_t)(b * 64 + row) * 26;
        const float* xp = x + (size_t)(b * 64 + p) * 26;
        unsigned w[4];
        #pragma unroll
        for (int h = 0; h < 4; ++h) {
            int k0 = gr * 8 + h * 2;
            int k1 = k0 + 1;
            float f0 = (k0 < 26) ? xq[k0] : (k0 < 52 ? xp[k0 - 26] : 0.f);
            float f1 = (k1 < 26) ? xq[k1] : (k1 < 52 ? xp[k1 - 26] : 0.f);
            w[h] = (unsigned)f2bf(f0) | ((unsigned)f2bf(f1) << 16);
        }
        *(u32x4*)((char*)xs + gr * 1024 + ((row ^ gr) << 4)) = (u32x4){w[0], w[1], w[2], w[3]};
    }

    int wave = t >> 6, lane = t & 63;
    int i16 = lane & 15, q4 = lane >> 4;

    f32x4 acc[4][4];

    // per-wave B pointers
    const unsigned short* Bb0base = Wp + wave * 32768 + lane * 8;  // global (incl. lane)
    unsigned short* Bw0 = Bst + wave * 2048;                       // DMA dest slot0 (uniform)
    unsigned short* Bw1 = Bw0 + 16384;                             // DMA dest slot1
    const char* Brd = (const char*)Bst + wave * 4096 + lane * 16;  // read base slot0

    __syncthreads();   // xs ready                                   [barrier 1]

    // ---- layer 0: h0 = relu([x_q|x_p] @ W0^T + b0), K=64 padded ----
    {
        #pragma unroll
        for (int mt = 0; mt < 4; ++mt)
            #pragma unroll
            for (int j = 0; j < 4; ++j)
                acc[mt][j] = (f32x4){0.f, 0.f, 0.f, 0.f};
        const unsigned short* Bw = W0p + wave * 4096 + lane * 8;
        const char* xb = (const char*)xs;
        #pragma unroll
        for (int s = 0; s < 2; ++s) {
            bf16x8 bfr[4];
            #pragma unroll
            for (int j = 0; j < 4; ++j)
                bfr[j] = *(const bf16x8*)(Bw + s * 2048 + j * 512);
            int g = s * 4 + q4;
            const char* A0 = xb + g * 1024 + ((i16 ^ g) << 4);
            #pragma unroll
            for (int mt = 0; mt < 4; ++mt) {
                bf16x8 a = *(const bf16x8*)(A0 + mt * 256);
                #pragma unroll
                for (int j = 0; j < 4; ++j)
                    acc[mt][j] = __builtin_amdgcn_mfma_f32_16x16x32_bf16(a, bfr[j], acc[mt][j], 0, 0, 0);
            }
        }
        // prime the B ring: slot0 <- layer-1 step 0 (all 4), then slot1 <- step 1
        #pragma unroll
        for (int j = 0; j < 4; ++j) GLDS16(Bb0base + j * 512,        Bw0 + j * 512);
        #pragma unroll
        for (int j = 0; j < 4; ++j) GLDS16(Bb0base + 2048 + j * 512, Bw1 + j * 512);
        store_h(acc, b0, hsm, wave, i16, q4, lane);   // h0 -> hsm (fresh, no hazard)
    }
    __syncthreads();   // h0 ready; drains priming DMAs (vmcnt 0)    [barrier 2]

    // ---- layers 1..3: B via LDS ring (counted-vmcnt DMA), A even/odd dbuf ----
    int A_even = (q4 << 10) + ((i16 ^ q4) << 4);
    const char* hbe = (const char*)hsm + A_even;               // even-step A base
    const char* hbo = (const char*)hsm + 4096 + (A_even ^ 64); // odd-step A base

    #pragma unroll 1
    for (int l = 0; l < 3; ++l) {
        const float* bl = (l == 0) ? b1 : (l == 1) ? b2 : b3;
        const unsigned short* Bb = Bb0base + (size_t)l * 262144;

        #pragma unroll
        for (int mt = 0; mt < 4; ++mt)
            #pragma unroll
            for (int j = 0; j < 4; ++j)
                acc[mt][j] = (f32x4){0.f, 0.f, 0.f, 0.f};

        // A(0)
        bf16x8 aE0 = *(const bf16x8*)(hbe);
        bf16x8 aE1 = *(const bf16x8*)(hbe + 256);
        bf16x8 aE2 = *(const bf16x8*)(hbe + 512);
        bf16x8 aE3 = *(const bf16x8*)(hbe + 768);
        bf16x8 aO0, aO1, aO2, aO3;

        #pragma unroll 1
        for (int s = 0; s < 16; s += 2) {
            // ===== even step s: B from slot0; DMA slot0 <- B(s+2) after use =====
            {
                WAIT_SLOT()   // slot0's DMAs (oldest 4 of <=8) landed
                bf16x8 b0v = *(const bf16x8*)(Brd);
                bf16x8 b1v = *(const bf16x8*)(Brd + 1024);
                bf16x8 b2v = *(const bf16x8*)(Brd + 2048);
                bf16x8 b3v = *(const bf16x8*)(Brd + 3072);
                const char* po = hbo + (s << 12);      // A(s+1)
                CLUSTER(aE0, aE1, aE2, aE3, b0v, 0)
                aO0 = *(const bf16x8*)(po);
                aO1 = *(const bf16x8*)(po + 256);
                CLUSTER(aE0, aE1, aE2, aE3, b1v, 1)
                aO2 = *(const bf16x8*)(po + 512);
                aO3 = *(const bf16x8*)(po + 768);
                CLUSTER(aE0, aE1, aE2, aE3, b2v, 2)
                CLUSTER(aE0, aE1, aE2, aE3, b3v, 3)
                // all 4 slot0 reads complete (DS in-order, cluster3 waited)
                int v = s + 2;
                const unsigned short* gsrc = (v < 16) ? Bb + v * 2048
                                           : (l < 2) ? Bb + 262144 + (v - 16) * 2048
                                                     : Bb + (v - 2) * 2048;   // dummy
                GLDS16(gsrc,        Bw0);
                GLDS16(gsrc + 512,  Bw0 + 512);
                GLDS16(gsrc + 1024, Bw0 + 1024);
                GLDS16(gsrc + 1536, Bw0 + 1536);
            }
            // ===== odd step s+1: B from slot1; DMA slot1 <- B(s+3) after use =====
            {
                WAIT_SLOT()   // slot1's DMAs landed
                bf16x8 b0v = *(const bf16x8*)(Brd + 32768);
                bf16x8 b1v = *(const bf16x8*)(Brd + 32768 + 1024);
                bf16x8 b2v = *(const bf16x8*)(Brd + 32768 + 2048);
                bf16x8 b3v = *(const bf16x8*)(Brd + 32768 + 3072);
                const char* pe = hbe + ((s + 2 < 16 ? s + 2 : 14) << 12);   // A(s+2)
                CLUSTER(aO0, aO1, aO2, aO3, b0v, 0)
                aE0 = *(const bf16x8*)(pe);
                aE1 = *(const bf16x8*)(pe + 256);
                CLUSTER(aO0, aO1, aO2, aO3, b1v, 1)
                aE2 = *(const bf16x8*)(pe + 512);
                aE3 = *(const bf16x8*)(pe + 768);
                CLUSTER(aO0, aO1, aO2, aO3, b2v, 2)
                CLUSTER(aO0, aO1, aO2, aO3, b3v, 3)
                int v = s + 3;
                const unsigned short* gsrc = (v < 16) ? Bb + v * 2048
                                           : (l < 2) ? Bb + 262144 + (v - 16) * 2048
                                                     : Bb + (v - 2) * 2048;   // dummy
                GLDS16(gsrc,        Bw1);
                GLDS16(gsrc + 512,  Bw1 + 512);
                GLDS16(gsrc + 1024, Bw1 + 1024);
                GLDS16(gsrc + 1536, Bw1 + 1536);
            }
        }

        if (l < 2) {
            __syncthreads();   // all reads of h done; drains DMAs   [barriers 3,5]
            store_h(acc, bl, hsm, wave, i16, q4, lane);
            __syncthreads();   // h ready                            [barriers 4,6]
        } else {
            // layer 3: bias + relu + sum over 64 rows -> per-block partial P[blk][col]
            #pragma unroll
            for (int j = 0; j < 4; ++j) {
                int col = (wave * 4 + j) * 16 + i16;
                float bb = bl[col];
                float sum = 0.f;
                #pragma unroll
                for (int mt = 0; mt < 4; ++mt)
                    #pragma unroll
                    for (int r = 0; r < 4; ++r)
                        sum += fmaxf(acc[mt][j][r] + bb, 0.f);
                sum += __shfl_xor(sum, 16);
                sum += __shfl_xor(sum, 32);
                if (q4 == 0) P[(size_t)blk * 512 + col] = sum;
            }
        }
    }
}

// ---------------- tail stage 1: reduce P over the 64 p-blocks -> Z ----
__global__ __launch_bounds__(64) void k_t1(const float* __restrict__ P,
                                           float* __restrict__ Z)
{
    int b = blockIdx.x >> 3, sl = blockIdx.x & 7;
    int col = sl * 64 + threadIdx.x;
    const float* Pb = P + (size_t)b * 64 * 512 + col;
    float s = 0.f;
    #pragma unroll 8
    for (int c = 0; c < 64; ++c) s += Pb[c * 512];
    Z[b * 512 + col] = s;
}

// ---------------- tail stage 2: layer 4 (768 -> 512), relu -> H4 ----
__global__ __launch_bounds__(256) void k_t2(
    const float* __restrict__ Z, const float* __restrict__ qst,
    const float* __restrict__ W4v, const float* __restrict__ b4,
    float* __restrict__ H4)
{
    int b = blockIdx.x >> 3, sl = blockIdx.x & 7;
    int t = threadIdx.x;
    __shared__ __align__(16) float z[768];
    __shared__ float ps[256];
    for (int i = t; i < 768; i += 256)
        z[i] = (i < 512) ? Z[b * 512 + i] : qst[b * 256 + (i - 512)];
    __syncthreads();
    int o = sl * 64 + (t & 63), hf = t >> 6;   // hf in [0,4)
    float acc = 0.f;
    const float4* Wv = (const float4*)W4v;
    const float4* z4 = (const float4*)z;
    #pragma unroll 4
    for (int kb = hf * 48; kb < hf * 48 + 48; ++kb) {
        float4 w = Wv[kb * 512 + o];
        float4 zz = z4[kb];
        acc = fmaf(w.x, zz.x, acc);
        acc = fmaf(w.y, zz.y, acc);
        acc = fmaf(w.z, zz.z, acc);
        acc = fmaf(w.w, zz.w, acc);
    }
    ps[t] = acc;
    __syncthreads();
    if (t < 64)
        H4[b * 512 + o] = fmaxf(ps[t] + ps[t + 64] + ps[t + 128] + ps[t + 192] + b4[o], 0.f);
}

// ---------------- tail stage 3: layer 5 (512 -> 512), relu -> H5 ----
__global__ __launch_bounds__(256) void k_t3(
    const float* __restrict__ H4,
    const float* __restrict__ W5v, const float* __restrict__ b5,
    float* __restrict__ H5)
{
    int b = blockIdx.x >> 3, sl = blockIdx.x & 7;
    int t = threadIdx.x;
    __shared__ __align__(16) float h4[512];
    __shared__ float ps[256];
    for (int i = t; i < 512; i += 256) h4[i] = H4[b * 512 + i];
    __syncthreads();
    int o = sl * 64 + (t & 63), hf = t >> 6;   // hf in [0,4)
    float acc = 0.f;
    const float4* Wv = (const float4*)W5v;
    const float4* h44 = (const float4*)h4;
    #pragma unroll 4
    for (int kb = hf * 32; kb < hf * 32 + 32; ++kb) {
        float4 w = Wv[kb * 512 + o];
        float4 hh = h44[kb];
        acc = fmaf(w.x, hh.x, acc);
        acc = fmaf(w.y, hh.y, acc);
        acc = fmaf(w.z, hh.z, acc);
        acc = fmaf(w.w, hh.w, acc);
    }
    ps[t] = acc;
    __syncthreads();
    if (t < 64)
        H5[b * 512 + o] = fmaxf(ps[t] + ps[t + 64] + ps[t + 128] + ps[t + 192] + b5[o], 0.f);
}

// ---------------- tail stage 4: layer 6 (512 -> 28) + log_softmax ----
__global__ __launch_bounds__(512) void k_t4(
    const float* __restrict__ H5,
    const float* __restrict__ W6, const float* __restrict__ b6,
    float* __restrict__ out)
{
    int b = blockIdx.x, t = threadIdx.x;
    __shared__ __align__(16) float h5[512];
    __shared__ float logits[28];
    __shared__ float red[2];
    h5[t] = H5[b * 512 + t];
    __syncthreads();
    {   // 16 lanes per output
        int o = t >> 4, c = t & 15;
        if (o < 28) {
            float acc = 0.f;
            for (int k = c; k < 512; k += 16) acc = fmaf(W6[o * 512 + k], h5[k], acc);
            acc += __shfl_xor(acc, 1);
            acc += __shfl_xor(acc, 2);
            acc += __shfl_xor(acc, 4);
            acc += __shfl_xor(acc, 8);
            if (c == 0) logits[o] = acc + b6[o];
        }
    }
    __syncthreads();
    if (t == 0) {
        float mx = -1e30f;
        for (int cc = 0; cc < 28; ++cc) mx = fmaxf(mx, logits[cc]);
        float se = 0.f;
        for (int cc = 0; cc < 28; ++cc) se += expf(logits[cc] - mx);
        red[0] = mx; red[1] = logf(se);
    }
    __syncthreads();
    if (t < 28) out[b * 28 + t] = logits[t] - red[0] - red[1];
}

extern "C" void kernel_launch(void* const* d_in, const int* in_sizes, int n_in,
                              void* d_out, int out_size, void* d_ws, size_t ws_size,
                              hipStream_t stream)
{
    const float* x   = (const float*)d_in[0];
    const float* qst = (const float*)d_in[1];
    const float* W0  = (const float*)d_in[2];
    const float* b0  = (const float*)d_in[3];
    const float* W1  = (const float*)d_in[4];
    const float* b1  = (const float*)d_in[5];
    const float* W2  = (const float*)d_in[6];
    const float* b2  = (const float*)d_in[7];
    const float* W3  = (const float*)d_in[8];
    const float* b3  = (const float*)d_in[9];
    const float* W4  = (const float*)d_in[10];
    const float* b4  = (const float*)d_in[11];
    const float* W5  = (const float*)d_in[12];
    const float* b5  = (const float*)d_in[13];
    const float* W6  = (const float*)d_in[14];
    const float* b6  = (const float*)d_in[15];
    float* out = (float*)d_out;

    char* ws = (char*)d_ws;
    unsigned short* Wp  = (unsigned short*)(ws);             // 1.5 MiB
    unsigned short* W0p = (unsigned short*)(ws + 1572864);   // 64 KiB
    float*          W4v = (float*)(ws + 1638400);            // 1.5 MiB
    float*          W5v = (float*)(ws + 3211264);            // 1 MiB
    float*          P   = (float*)(ws + 4259840);            // 4 MiB partials
    float*          Z   = (float*)(ws + 8454144);            // 64 KiB
    float*          H4  = (float*)(ws + 8519680);            // 64 KiB
    float*          H5  = (float*)(ws + 8585216);            // 64 KiB

    k_prep <<<NPV_TOTAL / 256, 256, 0, stream>>>(W1, W2, W3, W0, W4, W5,
                                                 Wp, W0p, W4v, W5v);
    k_fused<<<2048, 512, 0, stream>>>(x, Wp, W0p, b0, b1, b2, b3, P);
    k_t1   <<<256, 64, 0, stream>>>(P, Z);
    k_t2   <<<256, 256, 0, stream>>>(Z, qst, W4v, b4, H4);
    k_t3   <<<256, 256, 0, stream>>>(H4, W5v, b5, H5);
    k_t4   <<<32, 512, 0, stream>>>(H5, W6, b6, out);
}

// Round 19
// 315.127 us; speedup vs baseline: 1.0504x; 1.0504x over previous
//
#include <hip/hip_runtime.h>
#include <math.h>

// Relational Network fused pipeline for MI355X (gfx950).
// B=32, D=64, K=26, QST=256, G=[512x6, 28], AGG at layer 4.
//
// Round 24 = REVERT to round 21 verbatim (session best: 313.4us total,
// k_fused 234us @ VGPR 120, absmax 8.0).
//  - Round 23's async-DMA B ring was correct but SLOWER (265us, MfmaUtil
//    36%): the per-step blocking vmcnt wait + ~1-step prefetch distance +
//    the extra LDS round-trip (DMA->LDS->ds_read) lost to the X/Y register
//    double-buffer's direct flat-load pipeline. Both DMA variants measured;
//    that line is closed.
//  - k_fused: hsm double-buffer (4 barriers/block), fenced 4-MFMA clusters
//    (fence removal A/B'd neutral-to-worse in R20), X/Y B register dbuf
//    (2-step-ahead), A even/odd dbuf, next-layer B prefetch before store_h.
//  - k_prep vectorized (16B stores); tail split into 4 thin kernels at 8x
//    parallelism (R21: -8us vs monolithic k_tail).

typedef __attribute__((ext_vector_type(8))) short bf16x8;   // 8 bf16 in 4 VGPRs
typedef __attribute__((ext_vector_type(4))) float f32x4;    // MFMA 16x16 accumulator
typedef __attribute__((ext_vector_type(4))) unsigned int u32x4;

__device__ __forceinline__ unsigned short f2bf(float f) {
    union { float f; unsigned u; } x; x.f = f;
    unsigned r = x.u + 0x7fffu + ((x.u >> 16) & 1u);   // RNE
    return (unsigned short)(r >> 16);
}

// ---------------- pack / transpose weights (vectorized) ----------------
// Wp layout per layer: [wave(8)][s(16)][jj(4)][lane(64)][j(8)] bf16,
//   value = W[n][k], n = (wave*4+jj)*16 + (lane&15), k = s*32 + (lane>>4)*8 + j.
// W0p: same with s(2) over padded K=64 (k >= 52 -> 0).
// W4v/W5v: fp32 [k/4][512 out][4] so tail threads stream float4.
#define NPV_WP   98304            // 3 * 512 * 64   (8 bf16/thread)
#define NPV_W0P  4096             // 512 * 8        (8 bf16/thread)
#define NPV_W4   98304            // 768*512/4      (4 f32/thread)
#define NPV_W5   65536            // 512*512/4
#define NPV_TOTAL (NPV_WP + NPV_W0P + NPV_W4 + NPV_W5)   // 266240 = 1040*256
__global__ void k_prep(const float* __restrict__ W1, const float* __restrict__ W2,
                       const float* __restrict__ W3, const float* __restrict__ W0,
                       const float* __restrict__ W4, const float* __restrict__ W5,
                       unsigned short* __restrict__ Wp,   // [3][262144] bf16
                       unsigned short* __restrict__ W0p,  // [32768] bf16
                       float* __restrict__ W4v,           // [192][512][4] fp32
                       float* __restrict__ W5v)           // [128][512][4] fp32
{
    int f = blockIdx.x * 256 + threadIdx.x;
    if (f < NPV_WP) {
        int l = f >> 15, r = f & 32767;
        int n = r >> 6, kq = r & 63;                 // k0 = kq*8
        const float* W = (l == 0) ? W1 : (l == 1) ? W2 : W3;
        const float* src = W + n * 512 + kq * 8;
        int s = kq >> 2, q4 = kq & 3;
        int wv = n >> 6, jj = (n >> 4) & 3, i16 = n & 15;
        int lane = q4 * 16 + i16;
        unsigned w[4];
        #pragma unroll
        for (int h = 0; h < 4; ++h)
            w[h] = (unsigned)f2bf(src[h * 2]) | ((unsigned)f2bf(src[h * 2 + 1]) << 16);
        *(u32x4*)(Wp + (size_t)l * 262144 + ((((wv * 16 + s) * 4 + jj) * 64 + lane) << 3))
            = (u32x4){w[0], w[1], w[2], w[3]};
    } else if (f < NPV_WP + NPV_W0P) {
        int g = f - NPV_WP;
        int n = g >> 3, kq = g & 7;
        int s = kq >> 2, q4 = kq & 3;
        int wv = n >> 6, jj = (n >> 4) & 3, i16 = n & 15;
        int lane = q4 * 16 + i16;
        unsigned w[4];
        #pragma unroll
        for (int h = 0; h < 4; ++h) {
            int k0 = kq * 8 + h * 2, k1 = k0 + 1;
            float f0 = (k0 < 52) ? W0[n * 52 + k0] : 0.f;
            float f1 = (k1 < 52) ? W0[n * 52 + k1] : 0.f;
            w[h] = (unsigned)f2bf(f0) | ((unsigned)f2bf(f1) << 16);
        }
        *(u32x4*)(W0p + ((((wv * 2 + s) * 4 + jj) * 64 + lane) << 3))
            = (u32x4){w[0], w[1], w[2], w[3]};
    } else if (f < NPV_WP + NPV_W0P + NPV_W4) {
        int g = f - (NPV_WP + NPV_W0P);
        int o = g / 192, kb = g % 192;
        float4 w = *(const float4*)(W4 + (size_t)o * 768 + kb * 4);
        *(float4*)(W4v + (size_t)kb * 2048 + o * 4) = w;
    } else {
        int g = f - (NPV_WP + NPV_W0P + NPV_W4);
        int o = g >> 7, kb = g & 127;
        float4 w = *(const float4*)(W5 + (size_t)o * 512 + kb * 4);
        *(float4*)(W5v + (size_t)kb * 2048 + o * 4) = w;
    }
}

// ---------------- h-store epilogue: bias + relu + bf16 LDS write ----
// Granule-column-major target: byte = (col>>3)*1024 + (row ^ ((col>>3)&7))*16
//                                    + (col&7)*2.
// DPP quad_perm swap on f32, then v_cvt_pk_bf16_f32 packs (col, col+1) into
// one dword; even lanes write ds_write_b32.
__device__ __forceinline__ void store_h(const f32x4 (&acc)[4][4], const float* __restrict__ bl,
                                        unsigned short* hbuf, int wave, int i16, int q4, int lane)
{
    char* base = (char*)hbuf;
    #pragma unroll
    for (int j = 0; j < 4; ++j) {
        int col = (wave * 4 + j) * 16 + i16;
        int g = col >> 3;
        int e = g & 7;
        float bb = bl[col];
        char* colbase = base + g * 1024 + ((col & 7) << 1);
        #pragma unroll
        for (int mt = 0; mt < 4; ++mt) {
            #pragma unroll
            for (int r = 0; r < 4; ++r) {
                int row = mt * 16 + q4 * 4 + r;
                float v = fmaxf(acc[mt][j][r] + bb, 0.f);
                int vi = __float_as_int(v);
                // quad_perm [1,0,3,2]: each lane gets partner (lane^1)'s f32
                int swi = __builtin_amdgcn_update_dpp(0, vi, 0xB1, 0xF, 0xF, true);
                if ((lane & 1) == 0) {
                    unsigned pk;
                    asm("v_cvt_pk_bf16_f32 %0, %1, %2" : "=v"(pk) : "v"(vi), "v"(swi));
                    int slot = row ^ e;
                    *(unsigned*)(colbase + slot * 16) = pk;
                }
            }
        }
    }
}

#define CLUSTER(AV0, AV1, AV2, AV3, BV, JJ)                                              \
    __builtin_amdgcn_s_setprio(1);                                                      \
    acc[0][JJ] = __builtin_amdgcn_mfma_f32_16x16x32_bf16(AV0, BV, acc[0][JJ], 0, 0, 0); \
    acc[1][JJ] = __builtin_amdgcn_mfma_f32_16x16x32_bf16(AV1, BV, acc[1][JJ], 0, 0, 0); \
    acc[2][JJ] = __builtin_amdgcn_mfma_f32_16x16x32_bf16(AV2, BV, acc[2][JJ], 0, 0, 0); \
    acc[3][JJ] = __builtin_amdgcn_mfma_f32_16x16x32_bf16(AV3, BV, acc[3][JJ], 0, 0, 0); \
    __builtin_amdgcn_s_setprio(0);                                                      \
    __builtin_amdgcn_sched_barrier(0);

// ---------------- fused layers 0..3 ----------------
// One block per (b,p): 64 pair-rows. h tile 64x512 bf16, DOUBLE-BUFFERED in
// LDS: layer l reads hsm[l&1], writes hsm[(l+1)&1]. Granule-column-major
// within each buffer: [g=k>>3][slot=row^(g&7)][8 shorts].
// 8 waves; wave w computes cols [w*64, w*64+64): acc = 4 (row tiles) x 4 (col tiles).
__global__ __launch_bounds__(512, 2) void k_fused(
    const float* __restrict__ x,
    const unsigned short* __restrict__ Wp,
    const unsigned short* __restrict__ W0p,
    const float* __restrict__ b0, const float* __restrict__ b1,
    const float* __restrict__ b2, const float* __restrict__ b3,
    float* __restrict__ P)
{
    __shared__ __align__(16) unsigned short hsm[2 * 64 * 512];   // 128 KiB (2 bufs)
    __shared__ __align__(16) unsigned short xs[8 * 64 * 8];      // 8 KiB (x-pair tile)
    int t = threadIdx.x;
    int blk = blockIdx.x;
    int b = blk >> 6, p = blk & 63;

    // ---- stage xs: [g(8)][slot=row^g][8] bf16 of [x[b,row,:26] | x[b,p,:26] | 0] ----
    {
        int row = t >> 3, gr = t & 7;
        const float* xq = x + (size_t)(b * 64 + row) * 26;
        const float* xp = x + (size_t)(b * 64 + p) * 26;
        unsigned w[4];
        #pragma unroll
        for (int h = 0; h < 4; ++h) {
            int k0 = gr * 8 + h * 2;
            int k1 = k0 + 1;
            float f0 = (k0 < 26) ? xq[k0] : (k0 < 52 ? xp[k0 - 26] : 0.f);
            float f1 = (k1 < 26) ? xq[k1] : (k1 < 52 ? xp[k1 - 26] : 0.f);
            w[h] = (unsigned)f2bf(f0) | ((unsigned)f2bf(f1) << 16);
        }
        *(u32x4*)((char*)xs + gr * 1024 + ((row ^ gr) << 4)) = (u32x4){w[0], w[1], w[2], w[3]};
    }

    int wave = t >> 6, lane = t & 63;
    int i16 = lane & 15, q4 = lane >> 4;

    f32x4 acc[4][4];
    bf16x8 X0, X1, X2, X3, Y0, Y1, Y2, Y3;   // B stream dbuf, live across layers

    // per-wave B base for packed weights (layer stride 262144 shorts)
    const unsigned short* Bb0base = Wp + wave * 32768 + lane * 8;

    __syncthreads();   // xs ready                                   [barrier 1]

    // ---- layer 0: h0 = relu([x_q|x_p] @ W0^T + b0), K=64 padded ----
    {
        #pragma unroll
        for (int mt = 0; mt < 4; ++mt)
            #pragma unroll
            for (int j = 0; j < 4; ++j)
                acc[mt][j] = (f32x4){0.f, 0.f, 0.f, 0.f};
        const unsigned short* Bw0 = W0p + wave * 4096 + lane * 8;
        const char* xb = (const char*)xs;
        #pragma unroll
        for (int s = 0; s < 2; ++s) {
            bf16x8 bfr[4];
            #pragma unroll
            for (int j = 0; j < 4; ++j)
                bfr[j] = *(const bf16x8*)(Bw0 + s * 2048 + j * 512);
            int g = s * 4 + q4;
            const char* A0 = xb + g * 1024 + ((i16 ^ g) << 4);
            #pragma unroll
            for (int mt = 0; mt < 4; ++mt) {
                bf16x8 a = *(const bf16x8*)(A0 + mt * 256);
                #pragma unroll
                for (int j = 0; j < 4; ++j)
                    acc[mt][j] = __builtin_amdgcn_mfma_f32_16x16x32_bf16(a, bfr[j], acc[mt][j], 0, 0, 0);
            }
        }
        // prefetch layer-1 B(0)/B(1) NOW; latency hides under store_h below
        X0 = *(const bf16x8*)(Bb0base);
        X1 = *(const bf16x8*)(Bb0base + 512);
        X2 = *(const bf16x8*)(Bb0base + 1024);
        X3 = *(const bf16x8*)(Bb0base + 1536);
        Y0 = *(const bf16x8*)(Bb0base + 2048);
        Y1 = *(const bf16x8*)(Bb0base + 2560);
        Y2 = *(const bf16x8*)(Bb0base + 3072);
        Y3 = *(const bf16x8*)(Bb0base + 3584);
        store_h(acc, b0, hsm, wave, i16, q4, lane);   // h0 -> buf0
    }
    __syncthreads();   // buf0 ready                                 [barrier 2]

    // ---- layers 1..3: X/Y B-dbuf (2-step-ahead), A even/odd dbuf (1 ahead) ----
    int A_even = (q4 << 10) + ((i16 ^ q4) << 4);
    int A_odd  = 4096 + (A_even ^ 64);

    #pragma unroll 1
    for (int l = 0; l < 3; ++l) {
        const float* bl = (l == 0) ? b1 : (l == 1) ? b2 : b3;
        const unsigned short* Bb = Bb0base + (size_t)l * 262144;
        const char* hb = (const char*)hsm + (l & 1) * 65536;   // read buffer
        const char* hbe = hb + A_even;          // even-step A base
        const char* hbo = hb + A_odd;           // odd-step A base

        #pragma unroll
        for (int mt = 0; mt < 4; ++mt)
            #pragma unroll
            for (int j = 0; j < 4; ++j)
                acc[mt][j] = (f32x4){0.f, 0.f, 0.f, 0.f};

        // A(0)
        bf16x8 aE0 = *(const bf16x8*)(hbe);
        bf16x8 aE1 = *(const bf16x8*)(hbe + 256);
        bf16x8 aE2 = *(const bf16x8*)(hbe + 512);
        bf16x8 aE3 = *(const bf16x8*)(hbe + 768);
        bf16x8 aO0, aO1, aO2, aO3;

        #pragma unroll 1
        for (int s = 0; s < 16; s += 2) {
            // ===== even step s: consume aE*, X*; reload X = B(s+2), aO = A(s+1) =====
            {
                const unsigned short* BX = Bb + ((s + 2 < 16) ? (s + 2) : 14) * 2048;
                const char* po = hbo + (s << 12);      // A(s+1)
                CLUSTER(aE0, aE1, aE2, aE3, X0, 0)
                X0 = *(const bf16x8*)(BX);
                aO0 = *(const bf16x8*)(po);
                aO1 = *(const bf16x8*)(po + 256);
                CLUSTER(aE0, aE1, aE2, aE3, X1, 1)
                X1 = *(const bf16x8*)(BX + 512);
                aO2 = *(const bf16x8*)(po + 512);
                aO3 = *(const bf16x8*)(po + 768);
                CLUSTER(aE0, aE1, aE2, aE3, X2, 2)
                X2 = *(const bf16x8*)(BX + 1024);
                CLUSTER(aE0, aE1, aE2, aE3, X3, 3)
                X3 = *(const bf16x8*)(BX + 1536);
            }
            // ===== odd step s+1: consume aO*, Y*; reload Y = B(s+3), aE = A(s+2) =====
            {
                const unsigned short* BY = Bb + ((s + 3 < 16) ? (s + 3) : 15) * 2048;
                const char* pe = hbe + ((s + 2 < 16 ? s + 2 : 14) << 12);   // A(s+2)
                CLUSTER(aO0, aO1, aO2, aO3, Y0, 0)
                Y0 = *(const bf16x8*)(BY);
                aE0 = *(const bf16x8*)(pe);
                aE1 = *(const bf16x8*)(pe + 256);
                CLUSTER(aO0, aO1, aO2, aO3, Y1, 1)
                Y1 = *(const bf16x8*)(BY + 512);
                aE2 = *(const bf16x8*)(pe + 512);
                aE3 = *(const bf16x8*)(pe + 768);
                CLUSTER(aO0, aO1, aO2, aO3, Y2, 2)
                Y2 = *(const bf16x8*)(BY + 1024);
                CLUSTER(aO0, aO1, aO2, aO3, Y3, 3)
                Y3 = *(const bf16x8*)(BY + 1536);
            }
        }

        if (l < 2) {
            // prefetch NEXT layer's B(0)/B(1) before the epilogue; its L2
            // latency hides under store_h's VALU work (tail reloads above
            // were dead and are simply overwritten here)
            const unsigned short* Bn = Bb + 262144;
            X0 = *(const bf16x8*)(Bn);
            X1 = *(const bf16x8*)(Bn + 512);
            X2 = *(const bf16x8*)(Bn + 1024);
            X3 = *(const bf16x8*)(Bn + 1536);
            Y0 = *(const bf16x8*)(Bn + 2048);
            Y1 = *(const bf16x8*)(Bn + 2560);
            Y2 = *(const bf16x8*)(Bn + 3072);
            Y3 = *(const bf16x8*)(Bn + 3584);
            // write h_{l+1} into the OTHER buffer: no read-hazard barrier needed
            store_h(acc, bl, (unsigned short*)((char*)hsm + ((l + 1) & 1) * 65536),
                    wave, i16, q4, lane);
            __syncthreads();   // next buffer ready     [barriers 3,4]
        } else {
            // layer 3: bias + relu + sum over 64 rows -> per-block partial P[blk][col]
            #pragma unroll
            for (int j = 0; j < 4; ++j) {
                int col = (wave * 4 + j) * 16 + i16;
                float bb = bl[col];
                float sum = 0.f;
                #pragma unroll
                for (int mt = 0; mt < 4; ++mt)
                    #pragma unroll
                    for (int r = 0; r < 4; ++r)
                        sum += fmaxf(acc[mt][j][r] + bb, 0.f);
                sum += __shfl_xor(sum, 16);
                sum += __shfl_xor(sum, 32);
                if (q4 == 0) P[(size_t)blk * 512 + col] = sum;
            }
        }
    }
}

// ---------------- tail stage 1: reduce P over the 64 p-blocks -> Z ----
__global__ __launch_bounds__(64) void k_t1(const float* __restrict__ P,
                                           float* __restrict__ Z)
{
    int b = blockIdx.x >> 3, sl = blockIdx.x & 7;
    int col = sl * 64 + threadIdx.x;
    const float* Pb = P + (size_t)b * 64 * 512 + col;
    float s = 0.f;
    #pragma unroll 8
    for (int c = 0; c < 64; ++c) s += Pb[c * 512];
    Z[b * 512 + col] = s;
}

// ---------------- tail stage 2: layer 4 (768 -> 512), relu -> H4 ----
__global__ __launch_bounds__(256) void k_t2(
    const float* __restrict__ Z, const float* __restrict__ qst,
    const float* __restrict__ W4v, const float* __restrict__ b4,
    float* __restrict__ H4)
{
    int b = blockIdx.x >> 3, sl = blockIdx.x & 7;
    int t = threadIdx.x;
    __shared__ __align__(16) float z[768];
    __shared__ float ps[256];
    for (int i = t; i < 768; i += 256)
        z[i] = (i < 512) ? Z[b * 512 + i] : qst[b * 256 + (i - 512)];
    __syncthreads();
    int o = sl * 64 + (t & 63), hf = t >> 6;   // hf in [0,4)
    float acc = 0.f;
    const float4* Wv = (const float4*)W4v;
    const float4* z4 = (const float4*)z;
    #pragma unroll 4
    for (int kb = hf * 48; kb < hf * 48 + 48; ++kb) {
        float4 w = Wv[kb * 512 + o];
        float4 zz = z4[kb];
        acc = fmaf(w.x, zz.x, acc);
        acc = fmaf(w.y, zz.y, acc);
        acc = fmaf(w.z, zz.z, acc);
        acc = fmaf(w.w, zz.w, acc);
    }
    ps[t] = acc;
    __syncthreads();
    if (t < 64)
        H4[b * 512 + o] = fmaxf(ps[t] + ps[t + 64] + ps[t + 128] + ps[t + 192] + b4[o], 0.f);
}

// ---------------- tail stage 3: layer 5 (512 -> 512), relu -> H5 ----
__global__ __launch_bounds__(256) void k_t3(
    const float* __restrict__ H4,
    const float* __restrict__ W5v, const float* __restrict__ b5,
    float* __restrict__ H5)
{
    int b = blockIdx.x >> 3, sl = blockIdx.x & 7;
    int t = threadIdx.x;
    __shared__ __align__(16) float h4[512];
    __shared__ float ps[256];
    for (int i = t; i < 512; i += 256) h4[i] = H4[b * 512 + i];
    __syncthreads();
    int o = sl * 64 + (t & 63), hf = t >> 6;   // hf in [0,4)
    float acc = 0.f;
    const float4* Wv = (const float4*)W5v;
    const float4* h44 = (const float4*)h4;
    #pragma unroll 4
    for (int kb = hf * 32; kb < hf * 32 + 32; ++kb) {
        float4 w = Wv[kb * 512 + o];
        float4 hh = h44[kb];
        acc = fmaf(w.x, hh.x, acc);
        acc = fmaf(w.y, hh.y, acc);
        acc = fmaf(w.z, hh.z, acc);
        acc = fmaf(w.w, hh.w, acc);
    }
    ps[t] = acc;
    __syncthreads();
    if (t < 64)
        H5[b * 512 + o] = fmaxf(ps[t] + ps[t + 64] + ps[t + 128] + ps[t + 192] + b5[o], 0.f);
}

// ---------------- tail stage 4: layer 6 (512 -> 28) + log_softmax ----
__global__ __launch_bounds__(512) void k_t4(
    const float* __restrict__ H5,
    const float* __restrict__ W6, const float* __restrict__ b6,
    float* __restrict__ out)
{
    int b = blockIdx.x, t = threadIdx.x;
    __shared__ __align__(16) float h5[512];
    __shared__ float logits[28];
    __shared__ float red[2];
    h5[t] = H5[b * 512 + t];
    __syncthreads();
    {   // 16 lanes per output
        int o = t >> 4, c = t & 15;
        if (o < 28) {
            float acc = 0.f;
            for (int k = c; k < 512; k += 16) acc = fmaf(W6[o * 512 + k], h5[k], acc);
            acc += __shfl_xor(acc, 1);
            acc += __shfl_xor(acc, 2);
            acc += __shfl_xor(acc, 4);
            acc += __shfl_xor(acc, 8);
            if (c == 0) logits[o] = acc + b6[o];
        }
    }
    __syncthreads();
    if (t == 0) {
        float mx = -1e30f;
        for (int cc = 0; cc < 28; ++cc) mx = fmaxf(mx, logits[cc]);
        float se = 0.f;
        for (int cc = 0; cc < 28; ++cc) se += expf(logits[cc] - mx);
        red[0] = mx; red[1] = logf(se);
    }
    __syncthreads();
    if (t < 28) out[b * 28 + t] = logits[t] - red[0] - red[1];
}

extern "C" void kernel_launch(void* const* d_in, const int* in_sizes, int n_in,
                              void* d_out, int out_size, void* d_ws, size_t ws_size,
                              hipStream_t stream)
{
    const float* x   = (const float*)d_in[0];
    const float* qst = (const float*)d_in[1];
    const float* W0  = (const float*)d_in[2];
    const float* b0  = (const float*)d_in[3];
    const float* W1  = (const float*)d_in[4];
    const float* b1  = (const float*)d_in[5];
    const float* W2  = (const float*)d_in[6];
    const float* b2  = (const float*)d_in[7];
    const float* W3  = (const float*)d_in[8];
    const float* b3  = (const float*)d_in[9];
    const float* W4  = (const float*)d_in[10];
    const float* b4  = (const float*)d_in[11];
    const float* W5  = (const float*)d_in[12];
    const float* b5  = (const float*)d_in[13];
    const float* W6  = (const float*)d_in[14];
    const float* b6  = (const float*)d_in[15];
    float* out = (float*)d_out;

    char* ws = (char*)d_ws;
    unsigned short* Wp  = (unsigned short*)(ws);             // 1.5 MiB
    unsigned short* W0p = (unsigned short*)(ws + 1572864);   // 64 KiB
    float*          W4v = (float*)(ws + 1638400);            // 1.5 MiB
    float*          W5v = (float*)(ws + 3211264);            // 1 MiB
    float*          P   = (float*)(ws + 4259840);            // 4 MiB partials
    float*          Z   = (float*)(ws + 8454144);            // 64 KiB
    float*          H4  = (float*)(ws + 8519680);            // 64 KiB
    float*          H5  = (float*)(ws + 8585216);            // 64 KiB

    k_prep <<<NPV_TOTAL / 256, 256, 0, stream>>>(W1, W2, W3, W0, W4, W5,
                                                 Wp, W0p, W4v, W5v);
    k_fused<<<2048, 512, 0, stream>>>(x, Wp, W0p, b0, b1, b2, b3, P);
    k_t1   <<<256, 64, 0, stream>>>(P, Z);
    k_t2   <<<256, 256, 0, stream>>>(Z, qst, W4v, b4, H4);
    k_t3   <<<256, 256, 0, stream>>>(H4, W5v, b5, H5);
    k_t4   <<<32, 512, 0, stream>>>(H5, W6, b6, out);
}